// Round 1
// 112.991 us; speedup vs baseline: 1.3855x; 1.3855x over previous
//
#include <hip/hip_runtime.h>
#include <hip/hip_fp16.h>
#include <math.h>

namespace {
constexpr int kNB  = 16;
constexpr int kNA  = 1024;
constexpr int kP   = 65536;           // pairs per batch (power of 2)
constexpr int kNW  = 8;               // NWAVE
constexpr int kTot = kNB * kNA;       // 16384 atoms
constexpr int kMaxNei = 128;          // bucket capacity (mean 64, sigma 8)
constexpr float kInvCut = 1.0f / 6.0f;
constexpr float kPi = 3.14159265358979323846f;

constexpr int kChunkPairs = 4096;     // pairs per block (histogram chunk)
constexpr int kBuildThreads = 1024;   // threads per build block
constexpr int kPerThread = kChunkPairs / kBuildThreads;  // 4
}

// Phase A (rewritten): chunk-histogram slot reservation.
// One block = one 4096-pair chunk of one batch. Per-pair global atomics
// (1M, 64 same-dword each -> line-serialized RMW) are replaced by:
//   pass 1: LDS histogram over the batch's 1024 atoms; LDS atomicAdd
//           returns the within-chunk rank (payload kept in registers).
//   pass 2: ONE global atomicAdd per touched atom (~1006/chunk) reserves
//           a contiguous range in the bucket.
//   pass 3: scatter stores at base + rank.
// Global atomic count: 1M -> ~258K (4x), same-dword contention 64 -> 16.
// XCD swizzle preserved: batch b is handled by blocks with blockIdx%8==b%8,
// so bucket lines stay in one XCD's L2 for gather_density.
__global__ __launch_bounds__(kBuildThreads) void build_lists(
    const float* __restrict__ coords,   // [Tot*3]
    const int*   __restrict__ aidx,     // [NB*2*P]
    const float* __restrict__ shifts,   // [NB*P*3]
    int*   __restrict__ cnt,            // [Tot]
    uint2* __restrict__ lists)          // [Tot*kMaxNei], f16x4 payloads
{
  __shared__ int hist[kNA];             // pass1: counts; pass2+: bases

  const int tid = threadIdx.x;
  const int r = blockIdx.x & 7;                  // XCD slot
  const int q = blockIdx.x >> 3;                 // 0..31
  const int b = r + ((q >> 4) << 3);             // batch: r or r+8
  const int chunk = q & 15;                      // chunk within batch
  const int pairBase = chunk * kChunkPairs;

  if (tid < kNA) hist[tid] = 0;
  __syncthreads();

  uint2    pay[kPerThread];
  unsigned meta[kPerThread];             // bit31=active | rank<<10 | i0

#pragma unroll
  for (int it = 0; it < kPerThread; ++it) {
    const int p = pairBase + it * kBuildThreads + tid;

    const int i0 = __builtin_nontemporal_load(&aidx[(b * 2 + 0) * kP + p]);
    const int i1 = __builtin_nontemporal_load(&aidx[(b * 2 + 1) * kP + p]);
    const int gi = b * kNA + i0;
    const int gj = b * kNA + i1;

    const size_t sb = (size_t)(b * kP + p) * 3;
    const float sx = __builtin_nontemporal_load(&shifts[sb + 0]);
    const float sy = __builtin_nontemporal_load(&shifts[sb + 1]);
    const float sz = __builtin_nontemporal_load(&shifts[sb + 2]);
    const bool valid = (sx > -1.0e9f) & (sy > -1.0e9f) & (sz > -1.0e9f);

    const float dx = coords[gi * 3 + 0] - coords[gj * 3 + 0] + sx;
    const float dy = coords[gi * 3 + 1] - coords[gj * 3 + 1] + sy;
    const float dz = coords[gi * 3 + 2] - coords[gj * 3 + 2] + sz;

    const float dist = sqrtf(dx * dx + dy * dy + dz * dz);
    const float rr = dist * kInvCut;
    float f = 0.5f * (__cosf(kPi * fminf(rr, 1.0f)) + 1.0f);
    if (!valid | (rr >= 1.0f)) f = 0.0f;

    unsigned m = 0u;
    if (f != 0.0f) {
      const int rank = atomicAdd(&hist[i0], 1);   // LDS atomic: cheap
      m = 0x80000000u | ((unsigned)rank << 10) | (unsigned)i0;
      const __half2 h0 = __floats2half2_rn(dx, dy);
      const __half2 h1 = __floats2half2_rn(dz, f);
      pay[it].x = __builtin_bit_cast(unsigned, h0);
      pay[it].y = __builtin_bit_cast(unsigned, h1);
    }
    meta[it] = m;
  }
  __syncthreads();

  // Pass 2: one global atomic per touched atom reserves the bucket range.
  if (tid < kNA) {
    const int c = hist[tid];
    int base = 0;
    if (c > 0) base = atomicAdd(&cnt[b * kNA + tid], c);
    hist[tid] = base;                   // own-slot overwrite; no cross-read
  }
  __syncthreads();

  // Pass 3: scatter payloads at base + rank.
#pragma unroll
  for (int it = 0; it < kPerThread; ++it) {
    const unsigned m = meta[it];
    if (m & 0x80000000u) {
      const int lid  = (int)(m & 1023u);
      const int rank = (int)((m >> 10) & 0xFFFu);
      const int pos  = hist[lid] + rank;
      if (pos < kMaxNei) {
        lists[(size_t)(b * kNA + lid) * kMaxNei + pos] = pay[it];
      }
    }
  }
}

// Phase B: unchanged. 32 threads per atom (k = pair slice 0..3, w = wave
// channel 0..7). Block->batch mapping mirrors build_lists' XCD swizzle so
// bucket reads hit the same XCD's L2 that holds the dirty lines.
__global__ __launch_bounds__(256) void gather_density(
    const uint2* __restrict__ lists,    // [Tot*kMaxNei]
    const int*   __restrict__ cnt,      // [Tot]
    const int*   __restrict__ species,  // [Tot]
    const float* __restrict__ rs,       // [NTYPE*NWAVE]
    const float* __restrict__ inta,     // [NTYPE*NWAVE]
    const float* __restrict__ params,   // [NTYPE]
    float* __restrict__ out)            // [Tot*24]
{
  const int r = blockIdx.x & 7;
  const int m = blockIdx.x >> 3;                 // 0..255
  const int b = r + ((m >> 7) << 3);             // batch: r or r+8
  const int g = m & 127;                         // atom octet within batch
  const int i = b * kNA + g * 8 + (threadIdx.x >> 5);
  const int k = (threadIdx.x >> 3) & 3;          // pair slice
  const int w = threadIdx.x & 7;                 // wave channel

  const int s = species[i];
  const float rsw   = rs[s * kNW + w];
  const float intaw = inta[s * kNW + w];
  const int n = min(cnt[i], kMaxNei);
  const uint2* __restrict__ L = lists + (size_t)i * kMaxNei;

  float a[13];
#pragma unroll
  for (int mm = 0; mm < 13; ++mm) a[mm] = 0.0f;

#pragma unroll 4
  for (int j = k; j < n; j += 4) {
    const uint2 u = L[j];
    const float2 f0 = __half22float2(__builtin_bit_cast(__half2, u.x));
    const float2 f1 = __half22float2(__builtin_bit_cast(__half2, u.y));
    const float dxv = f0.x, dyv = f0.y, dzv = f1.x, f = f1.y;
    const float d2 = dxv * dxv + dyv * dyv + dzv * dzv;
    const float dist = sqrtf(d2);
    const float inv = (dist > 1e-12f) ? (1.0f / dist) : 1.0f;
    const float ux = dxv * inv, uy = dyv * inv, uz = dzv * inv;
    const float dr = dist - rsw;
    const float rad = __expf(-intaw * dr * dr);
    const float fr = f * rad;
    a[0] += fr;
    const float rx = fr * ux, ry = fr * uy, rz = fr * uz;
    a[1] += rx;        a[2] += ry;        a[3] += rz;
    a[4] += rx * ux;   a[5] += rx * uy;   a[6] += rx * uz;
    a[7] += ry * ux;   a[8] += ry * uy;   a[9] += ry * uz;
    a[10] += rz * ux;  a[11] += rz * uy;  a[12] += rz * uz;
  }

  // Reduce across the 4 k-slices (lanes differing in bits 3..4).
#pragma unroll
  for (int mm = 0; mm < 13; ++mm) {
    a[mm] += __shfl_xor(a[mm], 8);
    a[mm] += __shfl_xor(a[mm], 16);
  }

  if (k == 0) {
    const float pm = params[s];
    const float o0 = a[0] * a[0];
    const float o1 = a[1] * a[1] + a[2] * a[2] + a[3] * a[3];
    const float o2 = a[4] * a[4] + a[5] * a[5] + a[6] * a[6] +
                     a[7] * a[7] + a[8] * a[8] + a[9] * a[9] +
                     a[10] * a[10] + a[11] * a[11] + a[12] * a[12];
    float* o = out + (size_t)i * 24;
    o[0 * kNW + w] = pm * o0;
    o[1 * kNW + w] = pm * o1;
    o[2 * kNW + w] = pm * o2;
  }
}

extern "C" void kernel_launch(void* const* d_in, const int* in_sizes, int n_in,
                              void* d_out, int out_size, void* d_ws, size_t ws_size,
                              hipStream_t stream) {
  const float* coords  = (const float*)d_in[0];  // (16,1024,3)
  const int*   aidx    = (const int*)d_in[2];    // (16,2,65536)
  const float* shifts  = (const float*)d_in[3];  // (16,65536,3)
  const int*   species = (const int*)d_in[4];    // (16384,)
  const float* rs      = (const float*)d_in[5];  // (4,8)
  const float* inta    = (const float*)d_in[6];  // (4,8)
  const float* params  = (const float*)d_in[7];  // (4,)
  float* out = (float*)d_out;                    // (16384, 24)

  // Workspace: [cnt: 16384 int][lists: 16384*128 uint2 = 16 MB]
  int*   cnt   = (int*)d_ws;
  uint2* lists = (uint2*)((char*)d_ws + (size_t)kTot * sizeof(int));

  hipMemsetAsync(cnt, 0, (size_t)kTot * sizeof(int), stream);

  const int nchunks = (kNB * kP) / kChunkPairs;  // 256 blocks
  build_lists<<<nchunks, kBuildThreads, 0, stream>>>(coords, aidx, shifts,
                                                     cnt, lists);
  gather_density<<<(kTot * 32) / 256, 256, 0, stream>>>(lists, cnt, species,
                                                        rs, inta, params, out);
}

// Round 2
// 105.292 us; speedup vs baseline: 1.4868x; 1.0731x over previous
//
#include <hip/hip_runtime.h>
#include <hip/hip_fp16.h>
#include <math.h>

namespace {
constexpr int kNB  = 16;
constexpr int kNA  = 1024;
constexpr int kP   = 65536;           // pairs per batch (power of 2)
constexpr int kNW  = 8;               // NWAVE
constexpr int kTot = kNB * kNA;       // 16384 atoms
constexpr int kMaxNei = 128;          // bucket capacity (mean 64, sigma 8)
constexpr float kInvCut = 1.0f / 6.0f;
constexpr float kPi = 3.14159265358979323846f;

constexpr int kChunkPairs = 4096;     // pairs per block (histogram chunk)
constexpr int kBuildThreads = 1024;   // threads per build block
constexpr int kPerThread = kChunkPairs / kBuildThreads;  // 4
}

// Phase A: chunk-histogram slot reservation (proven round 1: 57 -> ~13 us).
// New this round: the payload is widened to 16 B and carries the FINISHED
// geometry {dist f32, f f32, (ux,uy) f16x2, uz f16} so gather's 8x-replicated
// w-channels no longer each redo sqrt/rcp/d2. dist/f are now exact f32
// (precision strictly improves vs the old f16 dx,dy,dz payload).
__global__ __launch_bounds__(kBuildThreads) void build_lists(
    const float* __restrict__ coords,   // [Tot*3]
    const int*   __restrict__ aidx,     // [NB*2*P]
    const float* __restrict__ shifts,   // [NB*P*3]
    int*   __restrict__ cnt,            // [Tot]
    uint4* __restrict__ lists)          // [Tot*kMaxNei], 16 B payloads
{
  __shared__ int hist[kNA];             // pass1: counts; pass2+: bases

  const int tid = threadIdx.x;
  const int r = blockIdx.x & 7;                  // XCD slot
  const int q = blockIdx.x >> 3;                 // 0..31
  const int b = r + ((q >> 4) << 3);             // batch: r or r+8
  const int chunk = q & 15;                      // chunk within batch
  const int pairBase = chunk * kChunkPairs;

  if (tid < kNA) hist[tid] = 0;
  __syncthreads();

  uint4    pay[kPerThread];
  unsigned meta[kPerThread];             // bit31=active | rank<<10 | i0

#pragma unroll
  for (int it = 0; it < kPerThread; ++it) {
    const int p = pairBase + it * kBuildThreads + tid;

    const int i0 = __builtin_nontemporal_load(&aidx[(b * 2 + 0) * kP + p]);
    const int i1 = __builtin_nontemporal_load(&aidx[(b * 2 + 1) * kP + p]);
    const int gi = b * kNA + i0;
    const int gj = b * kNA + i1;

    const size_t sb = (size_t)(b * kP + p) * 3;
    const float sx = __builtin_nontemporal_load(&shifts[sb + 0]);
    const float sy = __builtin_nontemporal_load(&shifts[sb + 1]);
    const float sz = __builtin_nontemporal_load(&shifts[sb + 2]);
    const bool valid = (sx > -1.0e9f) & (sy > -1.0e9f) & (sz > -1.0e9f);

    const float dx = coords[gi * 3 + 0] - coords[gj * 3 + 0] + sx;
    const float dy = coords[gi * 3 + 1] - coords[gj * 3 + 1] + sy;
    const float dz = coords[gi * 3 + 2] - coords[gj * 3 + 2] + sz;

    const float dist = sqrtf(dx * dx + dy * dy + dz * dz);
    const float rr = dist * kInvCut;
    float f = 0.5f * (__cosf(kPi * fminf(rr, 1.0f)) + 1.0f);
    if (!valid | (rr >= 1.0f)) f = 0.0f;

    unsigned m = 0u;
    if (f != 0.0f) {
      const int rank = atomicAdd(&hist[i0], 1);   // LDS atomic: cheap
      m = 0x80000000u | ((unsigned)rank << 10) | (unsigned)i0;
      const float inv = (dist > 1e-12f) ? (1.0f / dist) : 1.0f;
      const float ux = dx * inv, uy = dy * inv, uz = dz * inv;
      pay[it].x = __builtin_bit_cast(unsigned, dist);
      pay[it].y = __builtin_bit_cast(unsigned, f);
      pay[it].z = __builtin_bit_cast(unsigned, __floats2half2_rn(ux, uy));
      pay[it].w = __builtin_bit_cast(unsigned, __floats2half2_rn(uz, 0.0f));
    }
    meta[it] = m;
  }
  __syncthreads();

  // Pass 2: one global atomic per touched atom reserves the bucket range.
  if (tid < kNA) {
    const int c = hist[tid];
    int base = 0;
    if (c > 0) base = atomicAdd(&cnt[b * kNA + tid], c);
    hist[tid] = base;                   // own-slot overwrite; no cross-read
  }
  __syncthreads();

  // Pass 3: scatter 16 B payloads at base + rank.
#pragma unroll
  for (int it = 0; it < kPerThread; ++it) {
    const unsigned m = meta[it];
    if (m & 0x80000000u) {
      const int lid  = (int)(m & 1023u);
      const int rank = (int)((m >> 10) & 0xFFFu);
      const int pos  = hist[lid] + rank;
      if (pos < kMaxNei) {
        lists[(size_t)(b * kNA + lid) * kMaxNei + pos] = pay[it];
      }
    }
  }
}

// Phase B: 32 threads per atom (k = contiguous quarter-slice 0..3, w = wave
// channel 0..7). Payload carries finished geometry, so the inner loop is
// {unpack, dr, exp, fr, 13 fma} -- no sqrt/rcp replicated across w.
// Loads are one dwordx4 per payload, contiguous per thread, unroll-4 for MLP.
__global__ __launch_bounds__(256) void gather_density(
    const uint4* __restrict__ lists,    // [Tot*kMaxNei]
    const int*   __restrict__ cnt,      // [Tot]
    const int*   __restrict__ species,  // [Tot]
    const float* __restrict__ rs,       // [NTYPE*NWAVE]
    const float* __restrict__ inta,     // [NTYPE*NWAVE]
    const float* __restrict__ params,   // [NTYPE]
    float* __restrict__ out)            // [Tot*24]
{
  const int r = blockIdx.x & 7;
  const int m = blockIdx.x >> 3;                 // 0..255
  const int b = r + ((m >> 7) << 3);             // batch: r or r+8
  const int g = m & 127;                         // atom octet within batch
  const int i = b * kNA + g * 8 + (threadIdx.x >> 5);
  const int k = (threadIdx.x >> 3) & 3;          // quarter-slice
  const int w = threadIdx.x & 7;                 // wave channel

  const int s = species[i];
  const float rsw   = rs[s * kNW + w];
  const float intaw = inta[s * kNW + w];
  const int n = min(cnt[i], kMaxNei);
  const int Q = (n + 3) >> 2;                    // balanced slice length
  const int j0 = k * Q;                          // j0+Q-1 <= 127 always
  const uint4* __restrict__ L = lists + (size_t)i * kMaxNei;

  float a[13];
#pragma unroll
  for (int mm = 0; mm < 13; ++mm) a[mm] = 0.0f;

#pragma unroll 4
  for (int t = 0; t < Q; ++t) {
    const int j = j0 + t;
    const uint4 u = L[j];                        // safe: j < kMaxNei
    if (j < n) {                                 // predicate: slots >= n hold
      const float dist = __builtin_bit_cast(float, u.x);   // poison garbage
      const float f    = __builtin_bit_cast(float, u.y);
      const float2 uxy = __half22float2(__builtin_bit_cast(__half2, u.z));
      const float2 uzp = __half22float2(__builtin_bit_cast(__half2, u.w));
      const float ux = uxy.x, uy = uxy.y, uz = uzp.x;
      const float dr = dist - rsw;
      const float rad = __expf(-intaw * dr * dr);
      const float fr = f * rad;
      a[0] += fr;
      const float rx = fr * ux, ry = fr * uy, rz = fr * uz;
      a[1] += rx;        a[2] += ry;        a[3] += rz;
      a[4] += rx * ux;   a[5] += rx * uy;   a[6] += rx * uz;
      a[7] += ry * ux;   a[8] += ry * uy;   a[9] += ry * uz;
      a[10] += rz * ux;  a[11] += rz * uy;  a[12] += rz * uz;
    }
  }

  // Reduce across the 4 k-slices (lanes differing in bits 3..4).
#pragma unroll
  for (int mm = 0; mm < 13; ++mm) {
    a[mm] += __shfl_xor(a[mm], 8);
    a[mm] += __shfl_xor(a[mm], 16);
  }

  if (k == 0) {
    const float pm = params[s];
    const float o0 = a[0] * a[0];
    const float o1 = a[1] * a[1] + a[2] * a[2] + a[3] * a[3];
    const float o2 = a[4] * a[4] + a[5] * a[5] + a[6] * a[6] +
                     a[7] * a[7] + a[8] * a[8] + a[9] * a[9] +
                     a[10] * a[10] + a[11] * a[11] + a[12] * a[12];
    float* o = out + (size_t)i * 24;
    o[0 * kNW + w] = pm * o0;
    o[1 * kNW + w] = pm * o1;
    o[2 * kNW + w] = pm * o2;
  }
}

extern "C" void kernel_launch(void* const* d_in, const int* in_sizes, int n_in,
                              void* d_out, int out_size, void* d_ws, size_t ws_size,
                              hipStream_t stream) {
  const float* coords  = (const float*)d_in[0];  // (16,1024,3)
  const int*   aidx    = (const int*)d_in[2];    // (16,2,65536)
  const float* shifts  = (const float*)d_in[3];  // (16,65536,3)
  const int*   species = (const int*)d_in[4];    // (16384,)
  const float* rs      = (const float*)d_in[5];  // (4,8)
  const float* inta    = (const float*)d_in[6];  // (4,8)
  const float* params  = (const float*)d_in[7];  // (4,)
  float* out = (float*)d_out;                    // (16384, 24)

  // Workspace: [cnt: 16384 int = 64 KB][lists: 16384*128 uint4 = 32 MB]
  int*   cnt   = (int*)d_ws;
  uint4* lists = (uint4*)((char*)d_ws + (size_t)kTot * sizeof(int));

  hipMemsetAsync(cnt, 0, (size_t)kTot * sizeof(int), stream);

  const int nchunks = (kNB * kP) / kChunkPairs;  // 256 blocks
  build_lists<<<nchunks, kBuildThreads, 0, stream>>>(coords, aidx, shifts,
                                                     cnt, lists);
  gather_density<<<(kTot * 32) / 256, 256, 0, stream>>>(lists, cnt, species,
                                                        rs, inta, params, out);
}